// Round 3
// baseline (225.576 us; speedup 1.0000x reference)
//
#include <hip/hip_runtime.h>

typedef __bf16 bf16x8 __attribute__((ext_vector_type(8)));
typedef __bf16 bf16x2 __attribute__((ext_vector_type(2)));
typedef float f32x4 __attribute__((ext_vector_type(4)));
typedef unsigned int u32;
typedef unsigned short u16;

#define LOG2E 1.44269504088896f

__device__ __forceinline__ u32 pk2(float a, float b){
  bf16x2 v; v[0] = (__bf16)a; v[1] = (__bf16)b;
  return __builtin_bit_cast(u32, v);
}

// ---------------------------------------------------------------------------
// prep_w: build fragment-ordered bf16 weights.
// flat idx = ((cc*24+dt)*64 + lane)*8 + e  ->  W[d = dt*16+(lane&15)][c = cc*32+(lane>>4)*8+e]
// rows 0..63 = w_q, 64..127 = w_k, 128..383 = w_v
// ---------------------------------------------------------------------------
__global__ void prep_w(const float* __restrict__ wq, const float* __restrict__ wk,
                       const float* __restrict__ wv, u16* __restrict__ wfrag){
  int idx  = blockIdx.x * 256 + threadIdx.x;     // < 98304
  int e    = idx & 7;
  int lane = (idx >> 3) & 63;
  int f    = idx >> 9;                           // 0..191
  int cc = f / 24, dt = f % 24;
  int d = dt * 16 + (lane & 15);
  int c = cc * 32 + (lane >> 4) * 8 + e;
  float v;
  if (d < 64)       v = wq[d * 256 + c];
  else if (d < 128) v = wk[(d - 64) * 256 + c];
  else              v = wv[(d - 128) * 256 + c];
  __bf16 h = (__bf16)v;
  wfrag[idx] = __builtin_bit_cast(u16, h);
}

// ---------------------------------------------------------------------------
// proj_kernel: Out[d][n] = sum_c W[d][c] x[b][c][n] + bias.  128-n tiles.
//   Q written PRE-SCALED by log2(e), as [B][N][64] bf16 (d contiguous)
//   K written as [B][N][64] bf16
//   V written as [B][256][N] bf16 with each 64-column tile PERMUTED by pi^-1
//     (s = m5 m3 m2 m4 m1 m0) so attn's PV B-fragment needs no P shuffle.
// ---------------------------------------------------------------------------
__launch_bounds__(256, 1)
__global__ void proj_kernel(const float* __restrict__ x,
                            const float* __restrict__ bq, const float* __restrict__ bk,
                            const float* __restrict__ bv,
                            const u16* __restrict__ wfrag,
                            u16* __restrict__ qb, u16* __restrict__ kb, u16* __restrict__ vt)
{
  __shared__ u16 xlds[128 * 256];    // 64 KB, [n][c] rows 512B, 16B-slot swz ^(n&31)
  const int b    = blockIdx.x & 7;
  const int n0   = (blockIdx.x >> 3) * 128;      // 32 n-tiles of 128
  const int t    = threadIdx.x;
  const int lane = t & 63;
  const int w    = t >> 6;
  const int g    = lane >> 4, j = lane & 15;

  // ---- stage: transpose-convert x[b][:, n0..n0+127] into xlds[n][c] ----
  {
    const int n  = t & 127;
    const int ch = t >> 7;                       // c-half
    const float* xp = x + ((size_t)b * 256) * 4096 + n0 + n;
    char* lbase = reinterpret_cast<char*>(xlds);
    #pragma unroll
    for (int pass = 0; pass < 16; ++pass){
      int c = ch * 128 + pass * 8;
      float f0 = xp[(size_t)(c+0)*4096], f1 = xp[(size_t)(c+1)*4096];
      float f2 = xp[(size_t)(c+2)*4096], f3 = xp[(size_t)(c+3)*4096];
      float f4 = xp[(size_t)(c+4)*4096], f5 = xp[(size_t)(c+5)*4096];
      float f6 = xp[(size_t)(c+6)*4096], f7 = xp[(size_t)(c+7)*4096];
      uint4 q;
      q.x = pk2(f0, f1); q.y = pk2(f2, f3); q.z = pk2(f4, f5); q.w = pk2(f6, f7);
      u32 off = (u32)n * 512 + (((u32)c * 2) ^ (((u32)n & 31) << 4));
      *reinterpret_cast<uint4*>(lbase + off) = q;
    }
  }
  __syncthreads();

  // ---- GEMM: wave w owns d-tiles dt = w*6 .. w*6+5, 8 n-tiles ----
  f32x4 acc[6][8];
  #pragma unroll
  for (int i = 0; i < 6; ++i)
    #pragma unroll
    for (int nt = 0; nt < 8; ++nt) acc[i][nt] = f32x4{0.f,0.f,0.f,0.f};

  const char* lbase = reinterpret_cast<const char*>(xlds);
  for (int cc = 0; cc < 8; ++cc){
    bf16x8 a[6];
    #pragma unroll
    for (int i = 0; i < 6; ++i)
      a[i] = *reinterpret_cast<const bf16x8*>(wfrag + ((size_t)(cc*24 + w*6 + i) * 64 + lane) * 8);
    bf16x8 bb[8];
    #pragma unroll
    for (int nt = 0; nt < 8; ++nt){
      const u32 row = nt * 16 + j;
      const u32 off = row * 512 + (((u32)(cc * 64 + g * 16)) ^ ((row & 31) << 4));
      bb[nt] = *reinterpret_cast<const bf16x8*>(lbase + off);
    }
    #pragma unroll
    for (int i = 0; i < 6; ++i)
      #pragma unroll
      for (int nt = 0; nt < 8; ++nt)
        acc[i][nt] = __builtin_amdgcn_mfma_f32_16x16x32_bf16(a[i], bb[nt], acc[i][nt], 0, 0, 0);
  }

  // ---- epilogue: bias + convert + store ----
  #pragma unroll
  for (int i = 0; i < 6; ++i){
    const int dt = w * 6 + i;
    const int d0 = dt * 16;
    const int dd = d0 + 4 * g;   // this lane's 4 consecutive d rows
    if (d0 < 64){
      float b0 = bq[dd], b1 = bq[dd+1], b2 = bq[dd+2], b3 = bq[dd+3];
      #pragma unroll
      for (int nt = 0; nt < 8; ++nt){
        const int n = n0 + nt * 16 + j;
        uint2 u;
        u.x = pk2((acc[i][nt][0] + b0) * LOG2E, (acc[i][nt][1] + b1) * LOG2E);
        u.y = pk2((acc[i][nt][2] + b2) * LOG2E, (acc[i][nt][3] + b3) * LOG2E);
        *reinterpret_cast<uint2*>(qb + ((size_t)b * 4096 + n) * 64 + dd) = u;
      }
    } else if (d0 < 128){
      const int dk = dd - 64;
      float b0 = bk[dk], b1 = bk[dk+1], b2 = bk[dk+2], b3 = bk[dk+3];
      #pragma unroll
      for (int nt = 0; nt < 8; ++nt){
        const int n = n0 + nt * 16 + j;
        uint2 u;
        u.x = pk2(acc[i][nt][0] + b0, acc[i][nt][1] + b1);
        u.y = pk2(acc[i][nt][2] + b2, acc[i][nt][3] + b3);
        *reinterpret_cast<uint2*>(kb + ((size_t)b * 4096 + n) * 64 + dk) = u;
      }
    } else {
      const int dv = dd - 128;
      float b0 = bv[dv], b1 = bv[dv+1], b2 = bv[dv+2], b3 = bv[dv+3];
      #pragma unroll
      for (int nt = 0; nt < 8; ++nt){
        // permuted column within the 64-block: s = m5 m3 m2 m4 m1 m0, m = (nt&3)*16 + j
        const int nt4 = nt & 3;
        const int scol = ((nt4 & 2) << 4) | ((j & 12) << 1) | ((nt4 & 1) << 2) | (j & 3);
        const int n = n0 + (nt >> 2) * 64 + scol;
        u16* vp = vt + (size_t)b * 256 * 4096 + n;
        __bf16 h0 = (__bf16)(acc[i][nt][0] + b0);
        __bf16 h1 = (__bf16)(acc[i][nt][1] + b1);
        __bf16 h2 = (__bf16)(acc[i][nt][2] + b2);
        __bf16 h3 = (__bf16)(acc[i][nt][3] + b3);
        vp[(size_t)(dv+0) * 4096] = __builtin_bit_cast(u16, h0);
        vp[(size_t)(dv+1) * 4096] = __builtin_bit_cast(u16, h1);
        vp[(size_t)(dv+2) * 4096] = __builtin_bit_cast(u16, h2);
        vp[(size_t)(dv+3) * 4096] = __builtin_bit_cast(u16, h3);
      }
    }
  }
}

// ---------------------------------------------------------------------------
// attn_kernel v3: 512 blocks x 4 waves. Block = 64 q-rows, full 256 dv.
// Wave w = (col-half w&1: 32 q-cols) x (dv-half w>>1: 128 dv).
// S^T+softmax duplicated per dv-half (col-halves independent).
// Each K/V fragment read feeds 2 MFMAs (2 col-groups) -> LDS traffic halved.
// In-register P via m-permuted V (as r2). Defer-max THR=8. 8 waves/CU.
// ---------------------------------------------------------------------------
__launch_bounds__(256, 2)
__global__ void attn_kernel(const u16* __restrict__ qb, const u16* __restrict__ kb,
                            const u16* __restrict__ vt, float* __restrict__ out)
{
  __shared__ u16 kl[2][64 * 64];     // 16 KB  K tile [m][d], rows 128B, swz (m&7)<<4
  __shared__ u16 vl[2][256 * 64];    // 64 KB  V^T tile [dv][s], rows 128B, swz (dv&7)<<4

  const int b    = blockIdx.x & 7;
  const int qc   = blockIdx.x >> 3;            // 0..63
  const int t    = threadIdx.x, lane = t & 63, w = t >> 6;   // w: 0..3
  const int g    = lane >> 4, j = lane & 15;
  const int colh = w & 1;                      // col-half
  const int dvh  = (w >> 1) * 128;             // dv-half base

  const u16* Kg = kb + (size_t)b * 4096 * 64;
  const u16* Vg = vt + (size_t)b * 256 * 4096;

  // Q fragments (persistent, pre-scaled by log2e): qf[ng][kg]
  bf16x8 qf[2][2];
  #pragma unroll
  for (int ng = 0; ng < 2; ++ng){
    const u16* Qrow = qb + ((size_t)b * 4096 + qc * 64 + colh * 32 + ng * 16 + j) * 64;
    qf[ng][0] = *reinterpret_cast<const bf16x8*>(Qrow + 8 * g);
    qf[ng][1] = *reinterpret_cast<const bf16x8*>(Qrow + 32 + 8 * g);
  }

  f32x4 o[8][2];
  #pragma unroll
  for (int i = 0; i < 8; ++i){ o[i][0] = f32x4{0.f,0.f,0.f,0.f}; o[i][1] = f32x4{0.f,0.f,0.f,0.f}; }
  float mrun[2] = {-1.0e30f, -1.0e30f};
  float lrun[2] = {0.f, 0.f};

  auto stage = [&](int tile, int buf){
    const int m0 = tile * 64;
    #pragma unroll
    for (int i = 0; i < 2; ++i){             // K tile: 64 rows x 128B
      const int r = i * 32 + w * 8 + (lane >> 3);
      const char* src = reinterpret_cast<const char*>(Kg + (size_t)(m0 + r) * 64)
                        + ((((u32)lane & 7) * 16) ^ ((((u32)r) & 7) << 4));
      char* dst = reinterpret_cast<char*>(&kl[buf][0]) + i * 4096 + w * 1024;
      __builtin_amdgcn_global_load_lds((const __attribute__((address_space(1))) void*)src,
                                       (__attribute__((address_space(3))) void*)dst, 16, 0, 0);
    }
    #pragma unroll
    for (int i = 0; i < 8; ++i){             // V^T tile: 256 rows x 128B
      const int dv = i * 32 + w * 8 + (lane >> 3);
      const char* src = reinterpret_cast<const char*>(Vg + (size_t)dv * 4096 + m0)
                        + ((((u32)lane & 7) * 16) ^ (((u32)dv & 7) << 4));
      char* dst = reinterpret_cast<char*>(&vl[buf][0]) + i * 4096 + w * 1024;
      __builtin_amdgcn_global_load_lds((const __attribute__((address_space(1))) void*)src,
                                       (__attribute__((address_space(3))) void*)dst, 16, 0, 0);
    }
  };

  stage(0, 0);
  __syncthreads();

  const u32 vsw = ((u32)j & 7) << 4;   // V read swizzle (dv&7 == j&7, loop-invariant)

  for (int tile = 0; tile < 64; ++tile){
    const int cur = tile & 1;
    if (tile + 1 < 64) stage(tile + 1, cur ^ 1);

    const char* kbase = reinterpret_cast<const char*>(&kl[cur][0]);
    const char* vbase = reinterpret_cast<const char*>(&vl[cur][0]);

    // ---- S^T tile: s[ng][mt][r] = S2[m=16mt+4g+r][n = colh*32+ng*16+j] ----
    f32x4 s[2][4];
    __builtin_amdgcn_s_setprio(1);
    #pragma unroll
    for (int mt = 0; mt < 4; ++mt){
      const u32 row = mt * 16 + j;
      const u32 sw  = (row & 7) << 4;
      bf16x8 ka0 = *reinterpret_cast<const bf16x8*>(kbase + row * 128 + (((u32)(g * 16)) ^ sw));
      bf16x8 ka1 = *reinterpret_cast<const bf16x8*>(kbase + row * 128 + (((u32)(64 + g * 16)) ^ sw));
      #pragma unroll
      for (int ng = 0; ng < 2; ++ng){
        f32x4 z = f32x4{0.f,0.f,0.f,0.f};
        z = __builtin_amdgcn_mfma_f32_16x16x32_bf16(ka0, qf[ng][0], z, 0, 0, 0);
        z = __builtin_amdgcn_mfma_f32_16x16x32_bf16(ka1, qf[ng][1], z, 0, 0, 0);
        s[ng][mt] = z;
      }
    }
    __builtin_amdgcn_s_setprio(0);

    // ---- online softmax (base-2), per col-group ----
    float pmax[2];
    #pragma unroll
    for (int ng = 0; ng < 2; ++ng){
      float pm = s[ng][0][0];
      #pragma unroll
      for (int mt = 0; mt < 4; ++mt)
        #pragma unroll
        for (int r = 0; r < 4; ++r) pm = fmaxf(pm, s[ng][mt][r]);
      pm = fmaxf(pm, __shfl_xor(pm, 16));
      pm = fmaxf(pm, __shfl_xor(pm, 32));
      pmax[ng] = pm;
    }

    // defer-max: rescale only when some row's max grew past mrun + 8
    if (__any((pmax[0] > mrun[0] + 8.0f) || (pmax[1] > mrun[1] + 8.0f))){
      #pragma unroll
      for (int ng = 0; ng < 2; ++ng){
        const float mnew  = fmaxf(mrun[ng], pmax[ng]);
        const float alpha = __builtin_amdgcn_exp2f(mrun[ng] - mnew);
        mrun[ng] = mnew;
        lrun[ng] *= alpha;
        #pragma unroll
        for (int i = 0; i < 8; ++i){
          o[i][ng][0] *= alpha; o[i][ng][1] *= alpha;
          o[i][ng][2] *= alpha; o[i][ng][3] *= alpha;
        }
      }
    }

    bf16x8 pf[2][2];
    #pragma unroll
    for (int ng = 0; ng < 2; ++ng){
      float psum = 0.f;
      #pragma unroll
      for (int mt = 0; mt < 4; ++mt){
        float p0 = __builtin_amdgcn_exp2f(s[ng][mt][0] - mrun[ng]);
        float p1 = __builtin_amdgcn_exp2f(s[ng][mt][1] - mrun[ng]);
        float p2 = __builtin_amdgcn_exp2f(s[ng][mt][2] - mrun[ng]);
        float p3 = __builtin_amdgcn_exp2f(s[ng][mt][3] - mrun[ng]);
        psum += (p0 + p1) + (p2 + p3);
        pf[ng][mt >> 1][(mt & 1) * 4 + 0] = (__bf16)p0;
        pf[ng][mt >> 1][(mt & 1) * 4 + 1] = (__bf16)p1;
        pf[ng][mt >> 1][(mt & 1) * 4 + 2] = (__bf16)p2;
        pf[ng][mt >> 1][(mt & 1) * 4 + 3] = (__bf16)p3;
      }
      psum += __shfl_xor(psum, 16);
      psum += __shfl_xor(psum, 32);
      lrun[ng] += psum;
    }

    // ---- PV: O^T[dv][n] += V^T[dv][s] * P[s][n] ; pf IS the B-fragment ----
    __builtin_amdgcn_s_setprio(1);
    #pragma unroll
    for (int mc = 0; mc < 2; ++mc){
      #pragma unroll
      for (int dt = 0; dt < 8; ++dt){
        const u32 dv = dvh + dt * 16 + j;
        bf16x8 vf = *reinterpret_cast<const bf16x8*>(vbase + dv * 128 + (((u32)(mc * 64 + 16 * g)) ^ vsw));
        o[dt][0] = __builtin_amdgcn_mfma_f32_16x16x32_bf16(vf, pf[0][mc], o[dt][0], 0, 0, 0);
        o[dt][1] = __builtin_amdgcn_mfma_f32_16x16x32_bf16(vf, pf[1][mc], o[dt][1], 0, 0, 0);
      }
    }
    __builtin_amdgcn_s_setprio(0);

    __syncthreads();
  }

  // ---- epilogue: divide by l, store O^T coalesced ----
  #pragma unroll
  for (int ng = 0; ng < 2; ++ng){
    const float rinv = 1.0f / lrun[ng];
    const int n = qc * 64 + colh * 32 + ng * 16 + j;
    float* ob = out + (size_t)b * 256 * 4096 + n;
    #pragma unroll
    for (int dt = 0; dt < 8; ++dt){
      const int dv0 = dvh + dt * 16 + 4 * g;
      #pragma unroll
      for (int r = 0; r < 4; ++r)
        ob[(size_t)(dv0 + r) * 4096] = o[dt][ng][r] * rinv;
    }
  }
}

// ---------------------------------------------------------------------------
extern "C" void kernel_launch(void* const* d_in, const int* in_sizes, int n_in,
                              void* d_out, int out_size, void* d_ws, size_t ws_size,
                              hipStream_t stream)
{
  (void)in_sizes; (void)n_in; (void)out_size; (void)ws_size;
  const float* x  = (const float*)d_in[0];
  const float* wq = (const float*)d_in[1];
  const float* bq = (const float*)d_in[2];
  const float* wk = (const float*)d_in[3];
  const float* bk = (const float*)d_in[4];
  const float* wv = (const float*)d_in[5];
  const float* bv = (const float*)d_in[6];
  float* out = (float*)d_out;

  char* ws = (char*)d_ws;
  u16* qbuf  = (u16*)(ws + 0);            //  4 MB  [8][4096][64]  (pre-scaled by log2e)
  u16* kbuf  = (u16*)(ws + 4194304);      //  4 MB  [8][4096][64]
  u16* vbuf  = (u16*)(ws + 8388608);      // 16 MB  [8][256][4096] (m-permuted per 64-tile)
  u16* wfrag = (u16*)(ws + 25165824);     // 192 KB

  prep_w<<<dim3(384), dim3(256), 0, stream>>>(wq, wk, wv, wfrag);
  proj_kernel<<<dim3(256), dim3(256), 0, stream>>>(x, bq, bk, bv, wfrag, qbuf, kbuf, vbuf);
  attn_kernel<<<dim3(512), dim3(256), 0, stream>>>(qbuf, kbuf, vbuf, out);
}